// Round 4
// baseline (91.354 us; speedup 1.0000x reference)
//
#include <hip/hip_runtime.h>
#include <math.h>

#define B_ 8

// ws layout (floats): GY slabs, each of B_*(N+M) words:
//   slab s: [0, B_*N) dir0 per-target partial mins (over src chunk s)
//           [B_*N, B_*(N+M)) dir1 per-source partial mins (over tar chunk s)
// Blocks write plain stores to their own slab -> no init, no atomics.

// Fused both chamfer directions. blockIdx.z in [0, 2*B_):
//   z <  B_ : query = tar, min over src  -> "complete"
//   z >= B_ : query = src, min over tar  -> "accuracy"
// d^2 = |q|^2 + |p|^2 - 2 q.p. LDS tile {px,py,pz,|p|^2}; registers hold -2q;
// |q|^2 added after the min (monotone shift). Refs processed in pairs so the
// min folds to v_min3_f32: 3.5 VALU/pair core loop (floor ~11.9 us).
template <int QPT, int CHUNK>
__global__ __launch_bounds__(256) void minsq_kernel(
    const float* __restrict__ tar, const float* __restrict__ src,
    float* __restrict__ ws, int N, int M)
{
    const int z   = blockIdx.z;
    const int dir = (z >= B_) ? 1 : 0;
    const int b   = dir ? (z - B_) : z;
    const float* __restrict__ qry = dir ? src : tar;
    const float* __restrict__ pts = dir ? tar : src;
    const int K = dir ? M : N;   // number of query points
    const int L = dir ? N : M;   // number of reference points

    const int base = blockIdx.y * CHUNK;
    if (base >= L) return;                       // slab invalid for this dir
    const int cnt = min(CHUNK, L - base);

    const size_t slabStride = (size_t)B_ * (N + M);
    float* __restrict__ out = ws + (size_t)blockIdx.y * slabStride
                                 + (dir ? (size_t)B_ * N : (size_t)0)
                                 + (size_t)b * K;

    __shared__ float4 sp[CHUNK];
    const float* __restrict__ psrc = pts + ((size_t)b * L + base) * 3;
    const int t = threadIdx.x;
    for (int i = t; i < cnt; i += 256) {
        float px = psrc[3 * i + 0];
        float py = psrc[3 * i + 1];
        float pz = psrc[3 * i + 2];
        sp[i] = make_float4(px, py, pz, fmaf(px, px, fmaf(py, py, pz * pz)));
    }
    __syncthreads();

    const int qbase = blockIdx.x * (256 * QPT);
    float qx2[QPT], qy2[QPT], qz2[QPT], qw[QPT], mn[QPT];
#pragma unroll
    for (int k = 0; k < QPT; ++k) {
        int qi = qbase + k * 256 + t;
        if (qi < K) {
            const float* qp = qry + ((size_t)b * K + qi) * 3;
            float x = qp[0], y = qp[1], zc = qp[2];
            qx2[k] = -2.f * x; qy2[k] = -2.f * y; qz2[k] = -2.f * zc;
            qw[k] = fmaf(x, x, fmaf(y, y, zc * zc));
        } else {
            qx2[k] = 0.f; qy2[k] = 0.f; qz2[k] = 0.f; qw[k] = 0.f;
        }
        mn[k] = 3.4e38f;
    }

    if (cnt == CHUNK) {
#pragma unroll 4
        for (int j = 0; j < CHUNK; j += 2) {
            float4 p0 = sp[j];
            float4 p1 = sp[j + 1];
#pragma unroll
            for (int k = 0; k < QPT; ++k) {
                float d0 = fmaf(qx2[k], p0.x,
                           fmaf(qy2[k], p0.y,
                           fmaf(qz2[k], p0.z, p0.w)));
                float d1 = fmaf(qx2[k], p1.x,
                           fmaf(qy2[k], p1.y,
                           fmaf(qz2[k], p1.z, p1.w)));
                mn[k] = fminf(mn[k], fminf(d0, d1));   // -> v_min3_f32
            }
        }
    } else {
        int j = 0;
        for (; j + 1 < cnt; j += 2) {
            float4 p0 = sp[j];
            float4 p1 = sp[j + 1];
#pragma unroll
            for (int k = 0; k < QPT; ++k) {
                float d0 = fmaf(qx2[k], p0.x,
                           fmaf(qy2[k], p0.y,
                           fmaf(qz2[k], p0.z, p0.w)));
                float d1 = fmaf(qx2[k], p1.x,
                           fmaf(qy2[k], p1.y,
                           fmaf(qz2[k], p1.z, p1.w)));
                mn[k] = fminf(mn[k], fminf(d0, d1));
            }
        }
        if (j < cnt) {
            float4 p0 = sp[j];
#pragma unroll
            for (int k = 0; k < QPT; ++k) {
                float d0 = fmaf(qx2[k], p0.x,
                           fmaf(qy2[k], p0.y,
                           fmaf(qz2[k], p0.z, p0.w)));
                mn[k] = fminf(mn[k], d0);
            }
        }
    }

#pragma unroll
    for (int k = 0; k < QPT; ++k) {
        int qi = qbase + k * 256 + t;
        if (qi < K) {
            out[qi] = fmaxf(mn[k] + qw[k], 0.f);   // clamp roundoff negatives
        }
    }
}

// One-stage reduce: fold the per-slab partial mins, sqrt, stripe-sum, then
// atomicAdd scaled partials into d_out (zeroed by hipMemsetAsync upstream).
// outputs: d_out = {accuracy, complete, chamfer}.
template <int CHUNK>
__global__ __launch_bounds__(256) void reduce_kernel(
    const float* __restrict__ ws, float* __restrict__ outp, int N, int M)
{
    const int nt = B_ * N;                 // dir0 region -> complete
    const int ns = B_ * M;                 // dir1 region -> accuracy
    const size_t slabStride = (size_t)B_ * (N + M);
    const int nslab0 = (M + CHUNK - 1) / CHUNK;   // dir0 mins over src (L=M)
    const int nslab1 = (N + CHUNK - 1) / CHUNK;   // dir1 mins over tar (L=N)

    const int gid = blockIdx.x * 256 + threadIdx.x;
    const int stride = gridDim.x * 256;

    float s_t = 0.f, s_s = 0.f;
    for (int i = gid; i < nt; i += stride) {
        float m = ws[i];
        for (int s = 1; s < nslab0; ++s) m = fminf(m, ws[s * slabStride + i]);
        s_t += sqrtf(m);
    }
    for (int i = gid; i < ns; i += stride) {
        const size_t off = (size_t)nt + i;
        float m = ws[off];
        for (int s = 1; s < nslab1; ++s) m = fminf(m, ws[s * slabStride + off]);
        s_s += sqrtf(m);
    }

#pragma unroll
    for (int off = 32; off > 0; off >>= 1) {
        s_t += __shfl_down(s_t, off);
        s_s += __shfl_down(s_s, off);
    }
    __shared__ float rt[4], rs[4];
    const int wid = threadIdx.x >> 6, lid = threadIdx.x & 63;
    if (lid == 0) { rt[wid] = s_t; rs[wid] = s_s; }
    __syncthreads();
    if (threadIdx.x == 0) {
        float ct = (rt[0] + rt[1] + rt[2] + rt[3]) / (float)nt;  // complete part
        float ac = (rs[0] + rs[1] + rs[2] + rs[3]) / (float)ns;  // accuracy part
        atomicAdd(&outp[0], ac);
        atomicAdd(&outp[1], ct);
        atomicAdd(&outp[2], 0.5f * (ac + ct));
    }
}

extern "C" void kernel_launch(void* const* d_in, const int* in_sizes, int n_in,
                              void* d_out, int out_size, void* d_ws, size_t ws_size,
                              hipStream_t stream) {
    const float* tar = (const float*)d_in[0];
    const float* src = (const float*)d_in[1];
    const int N = in_sizes[0] / (B_ * 3);
    const int M = in_sizes[1] / (B_ * 3);
    float* ws = (float*)d_ws;
    float* outp = (float*)d_out;

    hipMemsetAsync(outp, 0, (size_t)out_size * sizeof(float), stream);

    constexpr int QPT = 4, CHUNK = 512;
    const int KL = (N > M) ? N : M;
    const int gx = (KL + 256 * QPT - 1) / (256 * QPT);
    const int gy = (KL + CHUNK - 1) / CHUNK;
    dim3 grid(gx, gy, 2 * B_);
    minsq_kernel<QPT, CHUNK><<<grid, dim3(256), 0, stream>>>(tar, src, ws, N, M);

    reduce_kernel<CHUNK><<<dim3(128), dim3(256), 0, stream>>>(ws, outp, N, M);
}